// Round 1
// baseline (650.173 us; speedup 1.0000x reference)
//
#include <hip/hip_runtime.h>
#include <hip/hip_bf16.h>
#include <math.h>

// Problem constants
#define NPIX 9216   // 96*96
#define HDIM 96
#define WDIM 96
#define NHEADS 6
#define BATCH 4

struct Bias6 { const float* p[6]; };

// ---------------------------------------------------------------------------
// fp32 GEMM: Y = W(MxK) * X(B x K x N), N = 9216.
// MODE 0: Y row-major [B][M][N]     (out projection -> d_out)
// MODE 1: Y is QKV pixel-records [B][6][NPIX][96]: slot = seg*32 + d,
//         seg = m/192 (0=q,1=k,2=v), head = (m%192)/32, d = m%32.
// Tile: 64(m) x 64(n) x 16(k); 256 threads, 4x4 microtile per thread.
// ---------------------------------------------------------------------------
template<int MODE>
__global__ __launch_bounds__(256) void gemm_f32(
    const float* __restrict__ Wm,   // [M][K]
    const float* __restrict__ X,    // [B][K][N]
    float* __restrict__ Y,
    int M, int K)
{
    const int N = NPIX;
    const int b  = blockIdx.z;
    const float* Xb = X + (size_t)b * K * N;
    const int n0 = blockIdx.x * 64;
    const int m0 = blockIdx.y * 64;

    __shared__ float sW[16][65];   // [k][m], +1 pad
    __shared__ float sX[16][64];   // [k][n]

    const int tid = threadIdx.x;
    const int tm = (tid >> 4) << 2;     // 0..60
    const int tn = (tid & 15) << 2;     // 0..60

    float acc[4][4];
    #pragma unroll
    for (int i = 0; i < 4; ++i)
        #pragma unroll
        for (int j = 0; j < 4; ++j) acc[i][j] = 0.f;

    const int lm = tid >> 2;            // 0..63 (m within tile)
    const int lk = (tid & 3) << 2;      // 0,4,8,12
    const int xk = tid >> 4;            // 0..15 (k within tile)
    const int xn = (tid & 15) << 2;     // 0..60

    for (int k0 = 0; k0 < K; k0 += 16) {
        float4 w4 = *(const float4*)&Wm[(size_t)(m0 + lm) * K + (k0 + lk)];
        float4 x4 = *(const float4*)&Xb[(size_t)(k0 + xk) * N + (n0 + xn)];
        sW[lk + 0][lm] = w4.x;
        sW[lk + 1][lm] = w4.y;
        sW[lk + 2][lm] = w4.z;
        sW[lk + 3][lm] = w4.w;
        *(float4*)&sX[xk][xn] = x4;
        __syncthreads();
        #pragma unroll
        for (int kk = 0; kk < 16; ++kk) {
            float w0 = sW[kk][tm + 0];
            float w1 = sW[kk][tm + 1];
            float w2 = sW[kk][tm + 2];
            float w3 = sW[kk][tm + 3];
            float4 xv = *(const float4*)&sX[kk][tn];
            acc[0][0] += w0 * xv.x; acc[0][1] += w0 * xv.y; acc[0][2] += w0 * xv.z; acc[0][3] += w0 * xv.w;
            acc[1][0] += w1 * xv.x; acc[1][1] += w1 * xv.y; acc[1][2] += w1 * xv.z; acc[1][3] += w1 * xv.w;
            acc[2][0] += w2 * xv.x; acc[2][1] += w2 * xv.y; acc[2][2] += w2 * xv.z; acc[2][3] += w2 * xv.w;
            acc[3][0] += w3 * xv.x; acc[3][1] += w3 * xv.y; acc[3][2] += w3 * xv.z; acc[3][3] += w3 * xv.w;
        }
        __syncthreads();
    }

    if (MODE == 0) {
        float* Yb = Y + (size_t)b * M * N;
        #pragma unroll
        for (int i = 0; i < 4; ++i) {
            float4 r = make_float4(acc[i][0], acc[i][1], acc[i][2], acc[i][3]);
            *(float4*)&Yb[(size_t)(m0 + tm + i) * N + (n0 + tn)] = r;
        }
    } else {
        const int seg = m0 / 192;              // 0=q,1=k,2=v (uniform per block)
        const int r = (m0 % 192) + tm;         // 0..191
        const int headIdx = r >> 5;            // 0..5
        const int d0 = r & 31;                 // multiple of 4
        float* Yb = Y + ((size_t)(b * NHEADS + headIdx) * NPIX) * 96 + seg * 32 + d0;
        #pragma unroll
        for (int j = 0; j < 4; ++j) {
            float4 t = make_float4(acc[0][j], acc[1][j], acc[2][j], acc[3][j]);
            *(float4*)&Yb[(size_t)(n0 + tn + j) * 96] = t;
        }
    }
}

// ---------------------------------------------------------------------------
// Neighborhood attention, thread-per-pixel, online softmax.
// qkv: [B][6][NPIX][96] pixel records (q 0:32, k 32:64, v 64:96)
// att: [B][192][NPIX] channel-major (ready for out-proj GEMM)
// ---------------------------------------------------------------------------
__global__ __launch_bounds__(256) void attn_kernel(
    const float* __restrict__ qkv, Bias6 bs, float* __restrict__ att)
{
    const int z = blockIdx.z;
    const int b = z / NHEADS, head = z % NHEADS;
    const int kszA[6] = {3, 5, 7, 7, 9, 9};
    const int dilA[6] = {1, 2, 1, 3, 1, 2};
    const int ksz = kszA[head];
    const int dil = dilA[head];
    const float* __restrict__ bias = bs.p[head];

    const int lane = threadIdx.x & 63;
    const int wv = threadIdx.x >> 6;
    const int w = blockIdx.x * 32 + (lane & 31);
    const int h = blockIdx.y * 8 + wv * 2 + (lane >> 5);
    const int pix = h * WDIM + w;

    const float* __restrict__ base = qkv + (size_t)(b * NHEADS + head) * NPIX * 96;
    const float* me = base + (size_t)pix * 96;

    float qr[32];
    #pragma unroll
    for (int d4 = 0; d4 < 8; ++d4) {
        float4 t = *(const float4*)(me + d4 * 4);
        qr[d4 * 4 + 0] = t.x; qr[d4 * 4 + 1] = t.y;
        qr[d4 * 4 + 2] = t.z; qr[d4 * 4 + 3] = t.w;
    }

    float m = -1e30f, l = 0.f;
    float acc[32];
    #pragma unroll
    for (int d = 0; d < 32; ++d) acc[d] = 0.f;

    const int cc = ksz >> 1;
    const float scale = 0.17677669529663689f;  // 1/sqrt(32)

    for (int i = 0; i < ksz; ++i) {
        const int hh = h + (i - cc) * dil;
        const bool rok = ((unsigned)hh < (unsigned)HDIM);
        for (int j = 0; j < ksz; ++j) {
            const int ww = w + (j - cc) * dil;
            const bool ok = rok && ((unsigned)ww < (unsigned)WDIM);
            float s = bias[i * ksz + j];
            const float* nb = base + (size_t)(hh * WDIM + ww) * 96;
            if (ok) {
                float dot = 0.f;
                #pragma unroll
                for (int d4 = 0; d4 < 8; ++d4) {
                    float4 k4 = *(const float4*)(nb + 32 + d4 * 4);
                    dot += qr[d4 * 4 + 0] * k4.x + qr[d4 * 4 + 1] * k4.y
                         + qr[d4 * 4 + 2] * k4.z + qr[d4 * 4 + 3] * k4.w;
                }
                s += dot * scale;
            }
            if (s > m) {
                const float f = __expf(m - s);   // first iter: exp(-huge)=0
                l *= f;
                #pragma unroll
                for (int d = 0; d < 32; ++d) acc[d] *= f;
                m = s;
                l += 1.f;
                if (ok) {
                    #pragma unroll
                    for (int d4 = 0; d4 < 8; ++d4) {
                        float4 v4 = *(const float4*)(nb + 64 + d4 * 4);
                        acc[d4 * 4 + 0] += v4.x; acc[d4 * 4 + 1] += v4.y;
                        acc[d4 * 4 + 2] += v4.z; acc[d4 * 4 + 3] += v4.w;
                    }
                }
            } else {
                const float e = __expf(s - m);
                l += e;
                if (ok) {
                    #pragma unroll
                    for (int d4 = 0; d4 < 8; ++d4) {
                        float4 v4 = *(const float4*)(nb + 64 + d4 * 4);
                        acc[d4 * 4 + 0] += e * v4.x; acc[d4 * 4 + 1] += e * v4.y;
                        acc[d4 * 4 + 2] += e * v4.z; acc[d4 * 4 + 3] += e * v4.w;
                    }
                }
            }
        }
    }

    const float inv = 1.f / l;
    float* ob = att + ((size_t)(b * 192 + head * 32)) * NPIX + pix;
    #pragma unroll
    for (int d = 0; d < 32; ++d) ob[(size_t)d * NPIX] = acc[d] * inv;
}

// ---------------------------------------------------------------------------
extern "C" void kernel_launch(void* const* d_in, const int* in_sizes, int n_in,
                              void* d_out, int out_size, void* d_ws, size_t ws_size,
                              hipStream_t stream) {
    const float* x     = (const float*)d_in[0];   // [4][192][96][96]
    const float* w_qkv = (const float*)d_in[1];   // [576][192]
    const float* w_out = (const float*)d_in[2];   // [192][192]
    Bias6 bs;
    for (int i = 0; i < 6; ++i) bs.p[i] = (const float*)d_in[3 + i];
    float* out = (float*)d_out;                   // [4][192][96][96]

    float* QKV = (float*)d_ws;                                   // [4][6][9216][96]
    float* ATT = QKV + (size_t)BATCH * NHEADS * NPIX * 96;       // [4][192][9216]

    // 1) qkv projection: M=576, K=192, pixel-record output
    gemm_f32<1><<<dim3(NPIX / 64, 576 / 64, BATCH), 256, 0, stream>>>(
        w_qkv, x, QKV, 576, 192);

    // 2) neighborhood attention per (b, head)
    attn_kernel<<<dim3(WDIM / 32, HDIM / 8, BATCH * NHEADS), 256, 0, stream>>>(
        QKV, bs, ATT);

    // 3) out projection: M=192, K=192, row-major into d_out
    gemm_f32<0><<<dim3(NPIX / 64, 192 / 64, BATCH), 256, 0, stream>>>(
        w_out, ATT, out, 192, 192);
}